// Round 2
// baseline (114.597 us; speedup 1.0000x reference)
//
#include <hip/hip_runtime.h>

#define FIELD 39
#define DIM 16
#define CROSS 741   // 39*38/2
#define BATCH 8192

// One wave = 4 rows; lane = rloc*16 + d. All 39 embeddings for (row,d) live in
// VGPRs (full unroll -> compile-time indices). Pair weights fw[] are staged in
// LDS and read as float4 broadcasts with compile-time offsets (ds_read_b128,
// in-order DS completion -> schedulable, no per-pair global/scalar load stalls).
__global__ __launch_bounds__(256) void fwfm_kernel(
    const int*   __restrict__ inputs,   // [BATCH][FIELD]
    const float* __restrict__ emb,      // [1M][DIM]
    const float* __restrict__ fw,       // [CROSS]
    const float* __restrict__ lw,       // [1M]
    const float* __restrict__ bias,     // [1]
    float*       __restrict__ out)      // [BATCH]
{
    __shared__ float fw_lds[CROSS + 3];   // pad to 744 = 186 float4

    const int tid = threadIdx.x;

    // ---- stage pair weights into LDS (3 KB, 3 rounds of 256) ----
    for (int p = tid; p < CROSS; p += 256) fw_lds[p] = fw[p];
    if (tid < 3) fw_lds[CROSS + tid] = 0.f;   // pad so the last float4 read is defined
    __syncthreads();

    const int lane = tid & 63;
    const int wave = tid >> 6;
    const int d    = lane & 15;       // dim owned by this lane
    const int rloc = lane >> 4;       // row within wave (0..3)
    const int row  = blockIdx.x * 16 + wave * 4 + rloc;

    const int* rowIdx = inputs + row * FIELD;

    // ---- indices (compile-time f -> registers; compiler merges into dwordx4) ----
    int idxv[FIELD];
    #pragma unroll
    for (int f = 0; f < FIELD; ++f) idxv[f] = rowIdx[f];

    // ---- gather embeddings: 16 consecutive lanes read one contiguous 64B row ----
    float e[FIELD];
    #pragma unroll
    for (int f = 0; f < FIELD; ++f)
        e[f] = emb[(size_t)idxv[f] * DIM + d];

    // ---- first order: 39 fields split across the 16 dim-lanes ----
    float fo = lw[idxv[d]] + lw[idxv[d + 16]];
    if (d + 32 < FIELD) fo += lw[idxv[d + 32]];

    // ---- second order: sum_i e_i * (sum_{j>i} fw_p * e_j), weights via LDS float4 ----
    const float4* fw4 = (const float4*)fw_lds;
    float wb[4];                       // current weight quad (registers)
    float acc0 = 0.f, acc1 = 0.f, acc2 = 0.f, acc3 = 0.f;
    int p = 0;
    #pragma unroll
    for (int i = 0; i < FIELD - 1; ++i) {
        float inner = 0.f;
        #pragma unroll
        for (int j = i + 1; j < FIELD; ++j) {
            if ((p & 3) == 0) {        // compile-time after unroll
                float4 w = fw4[p >> 2];   // ds_read_b128 broadcast, imm offset
                wb[0] = w.x; wb[1] = w.y; wb[2] = w.z; wb[3] = w.w;
            }
            inner = fmaf(wb[p & 3], e[j], inner);
            ++p;
        }
        // 4 rotating accumulators -> shorter dependent chain across i
        switch (i & 3) {
            case 0: acc0 = fmaf(e[i], inner, acc0); break;
            case 1: acc1 = fmaf(e[i], inner, acc1); break;
            case 2: acc2 = fmaf(e[i], inner, acc2); break;
            default: acc3 = fmaf(e[i], inner, acc3); break;
        }
    }
    float acc = (acc0 + acc1) + (acc2 + acc3);

    // ---- reduce the 16 dim-lanes of this row ----
    float tot = fo + acc;
    tot += __shfl_xor(tot, 1, 64);
    tot += __shfl_xor(tot, 2, 64);
    tot += __shfl_xor(tot, 4, 64);
    tot += __shfl_xor(tot, 8, 64);

    if (d == 0) out[row] = tot + bias[0];
}

extern "C" void kernel_launch(void* const* d_in, const int* in_sizes, int n_in,
                              void* d_out, int out_size, void* d_ws, size_t ws_size,
                              hipStream_t stream) {
    const int*   inputs = (const int*)  d_in[0];
    const float* emb    = (const float*)d_in[1];
    const float* fw     = (const float*)d_in[2];
    const float* lw     = (const float*)d_in[3];
    const float* bias   = (const float*)d_in[4];
    float*       out    = (float*)      d_out;

    dim3 grid(BATCH / 16);   // 512 blocks * 4 waves * 4 rows = 8192 rows
    fwfm_kernel<<<grid, 256, 0, stream>>>(inputs, emb, fw, lw, bias, out);
}

// Round 3
// 112.257 us; speedup vs baseline: 1.0208x; 1.0208x over previous
//
#include <hip/hip_runtime.h>
#include <utility>

#define FIELD 39
#define DIM 16
#define CROSS 741   // 39*38/2
#define BATCH 8192

// flat pair index of (i, i+1): number of pairs in rows < i
__host__ __device__ constexpr int pair_base(int i) {
    return i * (FIELD - 1) - i * (i - 1) / 2;
}

// ---- fold-expression helpers: every array index is a compile-time constant,
// ---- so SROA promotion of e[] to VGPRs is structurally guaranteed. ----

template <size_t... Fs>
__device__ __forceinline__ void gather_row(const int* __restrict__ rowIdx,
                                           const float* __restrict__ emb,
                                           int d, float (&e)[FIELD],
                                           std::index_sequence<Fs...>) {
    int idx[FIELD];
    ((idx[Fs] = rowIdx[Fs]), ...);                              // merged dwordx4 loads
    ((e[Fs] = emb[(size_t)idx[Fs] * DIM + d]), ...);            // 39 independent gathers
}

template <int I, size_t... Js>
__device__ __forceinline__ float row_inner(const float (&e)[FIELD],
                                           const float* __restrict__ fw,
                                           std::index_sequence<Js...>) {
    float s = 0.f;
    // fw[const]: wave-uniform address -> s_load (constant cache), batched x8/x16
    ((s = fmaf(fw[pair_base(I) + (int)Js], e[I + 1 + (int)Js], s)), ...);
    return s;
}

template <size_t... Is>
__device__ __forceinline__ float pair_sum(const float (&e)[FIELD],
                                          const float* __restrict__ fw,
                                          std::index_sequence<Is...>) {
    float acc[4] = {0.f, 0.f, 0.f, 0.f};   // constant-indexed -> promoted
    ((acc[Is & 3] = fmaf(e[Is],
                         row_inner<(int)Is>(e, fw, std::make_index_sequence<FIELD - 1 - Is>{}),
                         acc[Is & 3])),
     ...);
    return (acc[0] + acc[1]) + (acc[2] + acc[3]);
}

// One wave = 4 rows; lane = rloc*16 + d. All 39 embeddings for (row,d) in VGPRs.
__global__ __launch_bounds__(256) void fwfm_kernel(
    const int*   __restrict__ inputs,   // [BATCH][FIELD]
    const float* __restrict__ emb,      // [1M][DIM]
    const float* __restrict__ fw,       // [CROSS]
    const float* __restrict__ lw,       // [1M]
    const float* __restrict__ bias,     // [1]
    float*       __restrict__ out)      // [BATCH]
{
    const int tid  = threadIdx.x;
    const int lane = tid & 63;
    const int wave = tid >> 6;
    const int d    = lane & 15;       // dim owned by this lane
    const int rloc = lane >> 4;       // row within wave (0..3)
    const int row  = blockIdx.x * 16 + wave * 4 + rloc;

    const int* rowIdx = inputs + row * FIELD;

    // ---- gather embeddings: 16 consecutive lanes read one contiguous 64B row ----
    float e[FIELD];
    gather_row(rowIdx, emb, d, e, std::make_index_sequence<FIELD>{});

    // ---- first order: 39 fields split across the 16 dim-lanes.
    //      rowIdx[d] is a global load (runtime-indexed POINTER, not register array).
    float fo = lw[rowIdx[d]] + lw[rowIdx[d + 16]];
    if (d + 32 < FIELD) fo += lw[rowIdx[d + 32]];

    // ---- second order: sum_i e_i * (sum_{j>i} fw_p * e_j) ----
    float acc = pair_sum(e, fw, std::make_index_sequence<FIELD - 1>{});

    // ---- reduce the 16 dim-lanes of this row ----
    float tot = fo + acc;
    tot += __shfl_xor(tot, 1, 64);
    tot += __shfl_xor(tot, 2, 64);
    tot += __shfl_xor(tot, 4, 64);
    tot += __shfl_xor(tot, 8, 64);

    if (d == 0) out[row] = tot + bias[0];
}

extern "C" void kernel_launch(void* const* d_in, const int* in_sizes, int n_in,
                              void* d_out, int out_size, void* d_ws, size_t ws_size,
                              hipStream_t stream) {
    const int*   inputs = (const int*)  d_in[0];
    const float* emb    = (const float*)d_in[1];
    const float* fw     = (const float*)d_in[2];
    const float* lw     = (const float*)d_in[3];
    const float* bias   = (const float*)d_in[4];
    float*       out    = (float*)      d_out;

    dim3 grid(BATCH / 16);   // 512 blocks * 4 waves * 4 rows = 8192 rows
    fwfm_kernel<<<grid, 256, 0, stream>>>(inputs, emb, fw, lw, bias, out);
}

// Round 4
// 108.106 us; speedup vs baseline: 1.0600x; 1.0384x over previous
//
#include <hip/hip_runtime.h>
#include <utility>

#define FIELD 39
#define TILE  13      // 3 tiles of 13 = 39
#define DIM   16
#define BATCH 8192

// flat pair index of (i,j), i<j
__host__ __device__ constexpr int pair_base(int i) {
    return i * (FIELD - 1) - i * (i - 1) / 2;
}
__host__ __device__ constexpr int widx(int i, int j) {
    return pair_base(i) + (j - i - 1);
}

// ---- load tile T: 13 indices then 13 gathers; all indices compile-time ----
template <int T, size_t... Ks>
__device__ __forceinline__ void load_tile(const int* __restrict__ rowIdx,
                                          const float* __restrict__ emb,
                                          int d, float (&e)[TILE],
                                          std::index_sequence<Ks...>) {
    int idx[TILE];
    ((idx[Ks] = rowIdx[T * TILE + (int)Ks]), ...);
    ((e[Ks] = emb[(size_t)idx[Ks] * DIM + d]), ...);
}

// ---- off-diagonal block (A < B): all 13x13 pairs valid ----
template <int A, int B, int II, size_t... Js>
__device__ __forceinline__ float inner_off(const float (&eB)[TILE],
                                           const float* __restrict__ fw,
                                           std::index_sequence<Js...>) {
    float s = 0.f;
    // fw[constexpr]: wave-uniform -> batched s_load from constant cache
    ((s = fmaf(fw[widx(A * TILE + II, B * TILE + (int)Js)], eB[Js], s)), ...);
    return s;
}
template <int A, int B, size_t... Is>
__device__ __forceinline__ void block_off(const float (&eA)[TILE],
                                          const float (&eB)[TILE],
                                          const float* __restrict__ fw,
                                          float (&acc)[4],
                                          std::index_sequence<Is...>) {
    ((acc[Is & 3] = fmaf(eA[Is],
                         inner_off<A, B, (int)Is>(eB, fw, std::make_index_sequence<TILE>{}),
                         acc[Is & 3])),
     ...);
}

// ---- diagonal block: triangular ii < jj within the tile ----
template <int A, int II, size_t... Js>
__device__ __forceinline__ float inner_diag(const float (&e)[TILE],
                                            const float* __restrict__ fw,
                                            std::index_sequence<Js...>) {
    float s = 0.f;
    ((s = fmaf(fw[widx(A * TILE + II, A * TILE + II + 1 + (int)Js)],
               e[II + 1 + Js], s)),
     ...);
    return s;
}
template <int A, size_t... Is>
__device__ __forceinline__ void block_diag(const float (&e)[TILE],
                                           const float* __restrict__ fw,
                                           float (&acc)[4],
                                           std::index_sequence<Is...>) {
    ((acc[Is & 3] = fmaf(e[Is],
                         inner_diag<A, (int)Is>(e, fw,
                             std::make_index_sequence<TILE - 1 - Is>{}),
                         acc[Is & 3])),
     ...);
}

// One wave = 4 rows; lane = rloc*16 + d. Peak live state: eA[13]+eB[13]+acc[4]
// + transients ~= 55 VGPRs -> no spill, allocator has slack to batch s_loads.
__global__ __launch_bounds__(256) void fwfm_kernel(
    const int*   __restrict__ inputs,   // [BATCH][FIELD]
    const float* __restrict__ emb,      // [1M][DIM]
    const float* __restrict__ fw,       // [741]
    const float* __restrict__ lw,       // [1M]
    const float* __restrict__ bias,     // [1]
    float*       __restrict__ out)      // [BATCH]
{
    const int tid  = threadIdx.x;
    const int lane = tid & 63;
    const int wave = tid >> 6;
    const int d    = lane & 15;       // dim owned by this lane
    const int rloc = lane >> 4;       // row within wave (0..3)
    const int row  = blockIdx.x * 16 + wave * 4 + rloc;

    const int* rowIdx = inputs + row * FIELD;

    // ---- first order: 39 fields split across the 16 dim-lanes ----
    float fo = lw[rowIdx[d]] + lw[rowIdx[d + 16]];
    if (d < 7) fo += lw[rowIdx[d + 32]];

    // ---- second order over 3x3 tile blocks ----
    float eA[TILE], eB[TILE];
    float acc[4] = {0.f, 0.f, 0.f, 0.f};
    const auto seqT = std::make_index_sequence<TILE>{};

    load_tile<0>(rowIdx, emb, d, eA, seqT);      // tile0 -> eA
    block_diag<0>(eA, fw, acc, seqT);
    load_tile<1>(rowIdx, emb, d, eB, seqT);      // tile1 -> eB
    block_off<0, 1>(eA, eB, fw, acc, seqT);
    load_tile<2>(rowIdx, emb, d, eB, seqT);      // tile2 -> eB
    block_off<0, 2>(eA, eB, fw, acc, seqT);
    load_tile<1>(rowIdx, emb, d, eA, seqT);      // tile1 reload (L1/L2-hot) -> eA
    block_diag<1>(eA, fw, acc, seqT);
    block_off<1, 2>(eA, eB, fw, acc, seqT);      // eB still tile2
    block_diag<2>(eB, fw, acc, seqT);            // eB still tile2
    float so = (acc[0] + acc[1]) + (acc[2] + acc[3]);

    // ---- reduce the 16 dim-lanes of this row ----
    float tot = fo + so;
    tot += __shfl_xor(tot, 1, 64);
    tot += __shfl_xor(tot, 2, 64);
    tot += __shfl_xor(tot, 4, 64);
    tot += __shfl_xor(tot, 8, 64);

    if (d == 0) out[row] = tot + bias[0];
}

extern "C" void kernel_launch(void* const* d_in, const int* in_sizes, int n_in,
                              void* d_out, int out_size, void* d_ws, size_t ws_size,
                              hipStream_t stream) {
    const int*   inputs = (const int*)  d_in[0];
    const float* emb    = (const float*)d_in[1];
    const float* fw     = (const float*)d_in[2];
    const float* lw     = (const float*)d_in[3];
    const float* bias   = (const float*)d_in[4];
    float*       out    = (float*)      d_out;

    dim3 grid(BATCH / 16);   // 512 blocks * 4 waves * 4 rows = 8192 rows
    fwfm_kernel<<<grid, 256, 0, stream>>>(inputs, emb, fw, lw, bias, out);
}